// Round 1
// 282.418 us; speedup vs baseline: 1.0514x; 1.0514x over previous
//
#include <hip/hip_runtime.h>
#include <hip/hip_fp16.h>

typedef _Float16 f16x8 __attribute__((ext_vector_type(8)));
typedef _Float16 f16x4 __attribute__((ext_vector_type(4)));
typedef float f32x4 __attribute__((ext_vector_type(4)));

// ================= bucketed CSR build =================
#define BSH 9
#define BSZ 512
#define CAP 12288

__global__ __launch_bounds__(256) void passA(const int* __restrict__ ei,
                                             int* __restrict__ bcount, int E, int NB) {
  __shared__ int hist[256];
  int t = threadIdx.x;
  hist[t] = 0;
  __syncthreads();
  for (int e = blockIdx.x * 256 + t; e < E; e += gridDim.x * 256)
    atomicAdd(&hist[ei[E + e] >> BSH], 1);
  __syncthreads();
  if (t < NB && hist[t]) atomicAdd(&bcount[t], hist[t]);
}

__global__ __launch_bounds__(256) void scanB(const int* __restrict__ bcount,
                                             int* __restrict__ bstart,
                                             int* __restrict__ bfill, int NB, int E) {
  __shared__ int s[256];
  int t = threadIdx.x;
  int v = (t < NB) ? bcount[t] : 0;
  s[t] = v;
  __syncthreads();
  for (int off = 1; off < 256; off <<= 1) {
    int add = (t >= off) ? s[t - off] : 0;
    __syncthreads();
    s[t] += add;
    __syncthreads();
  }
  if (t < NB) {
    int ex = s[t] - v;
    bstart[t] = ex;
    bfill[t] = ex;
  }
  if (t == 0) bstart[NB] = E;
}

// ============ MFMA GEMM body: G = (X @ W) [* dinv] -> fp16 ============
template <int NC, int NWC, bool IN_F16, bool SCALE>
__device__ __forceinline__ void gemm_mfma_body(
    const void* __restrict__ Xv, const float* __restrict__ W,
    const float* __restrict__ dinv, _Float16* __restrict__ G, int nrows, int bid,
    _Float16* Bs) {
  int t = threadIdx.x;
  {
    int n = t % NC;
    int kh = (t / NC) * (NC / 2);
    constexpr int NBLK = (NC / 2) / 8;
#pragma unroll
    for (int b = 0; b < NBLK; ++b) {
      f16x8 tmp;
#pragma unroll
      for (int j = 0; j < 8; ++j)
        tmp[j] = (_Float16)W[(size_t)(kh + b * 8 + j) * NC + n];
      *(f16x8*)(&Bs[n * 136 + kh + b * 8]) = tmp;
    }
  }
  __syncthreads();

  int w = t >> 6, lane = t & 63;
  int m = lane & 15, q = lane >> 4;
  int wr = (w / NWC) * 64, wc = (w % NWC) * 64;
  int row0 = bid * ((4 / NWC) * 64);

  f32x4 acc[4][4];
#pragma unroll
  for (int rt = 0; rt < 4; ++rt)
#pragma unroll
    for (int ct = 0; ct < 4; ++ct)
#pragma unroll
      for (int qq = 0; qq < 4; ++qq) acc[rt][ct][qq] = 0.f;

#pragma unroll
  for (int kc = 0; kc < 4; ++kc) {
    int kbase = kc * 32 + q * 8;
    f16x8 af[4];
#pragma unroll
    for (int rt = 0; rt < 4; ++rt) {
      int row = row0 + wr + rt * 16 + m;
      if constexpr (IN_F16) {
        f16x8 a = {0, 0, 0, 0, 0, 0, 0, 0};
        if (row < nrows) a = *(const f16x8*)((const _Float16*)Xv + (size_t)row * 128 + kbase);
        af[rt] = a;
      } else {
        float4 x0 = {0, 0, 0, 0}, x1 = {0, 0, 0, 0};
        if (row < nrows) {
          const float* Xf = (const float*)Xv;
          x0 = *(const float4*)(Xf + (size_t)row * 128 + kbase);
          x1 = *(const float4*)(Xf + (size_t)row * 128 + kbase + 4);
        }
        f16x8 a;
        a[0] = (_Float16)x0.x; a[1] = (_Float16)x0.y;
        a[2] = (_Float16)x0.z; a[3] = (_Float16)x0.w;
        a[4] = (_Float16)x1.x; a[5] = (_Float16)x1.y;
        a[6] = (_Float16)x1.z; a[7] = (_Float16)x1.w;
        af[rt] = a;
      }
    }
    f16x8 bf[4];
#pragma unroll
    for (int ct = 0; ct < 4; ++ct) {
      int n = wc + ct * 16 + m;
      bf[ct] = *(f16x8*)(&Bs[n * 136 + kbase]);
    }
#pragma unroll
    for (int rt = 0; rt < 4; ++rt)
#pragma unroll
      for (int ct = 0; ct < 4; ++ct)
        acc[rt][ct] = __builtin_amdgcn_mfma_f32_16x16x32_f16(af[rt], bf[ct],
                                                             acc[rt][ct], 0, 0, 0);
  }
#pragma unroll
  for (int rt = 0; rt < 4; ++rt) {
#pragma unroll
    for (int r = 0; r < 4; ++r) {
      int row = row0 + wr + rt * 16 + q * 4 + r;
      if (row < nrows) {
        float d = SCALE ? dinv[row] : 1.f;
#pragma unroll
        for (int ct = 0; ct < 4; ++ct) {
          int col = wc + ct * 16 + m;
          G[(size_t)row * NC + col] = (_Float16)(acc[rt][ct][r] * d);
        }
      }
    }
  }
}

// ===== fused: gemm1 (MFMA, unscaled, fp32-in) interleaved with passB =====
__global__ __launch_bounds__(256) void fused_gemm_passB(
    const float* __restrict__ X, const float* __restrict__ W1,
    _Float16* __restrict__ G, int nrows, int GB,
    const int* __restrict__ ei, int* __restrict__ bfill,
    unsigned int* __restrict__ pairs, int E, int PB) {
  __shared__ char smem[128 * 136 * 2];
  int g = blockIdx.x;
  int M2 = 2 * (GB < PB ? GB : PB);
  bool is_gemm;
  int bid;
  if (g < M2) { is_gemm = (g & 1) == 0; bid = g >> 1; }
  else        { is_gemm = (GB > PB);    bid = g - M2 + (GB < PB ? GB : PB); }
  if (is_gemm) {
    gemm_mfma_body<128, 2, false, false>(X, W1, nullptr, G, nrows, bid,
                                         (_Float16*)smem);
  } else {
    int* hist = (int*)smem;
    int* gbase = (int*)(smem + 1024);
    int t = threadIdx.x;
    hist[t] = 0;
    __syncthreads();
    int d[8], s[8], lp[8], bb[8];
    int base = bid * 2048;
#pragma unroll
    for (int u = 0; u < 8; ++u) {
      int e = base + u * 256 + t;
      if (e < E) {
        d[u] = ei[E + e];
        s[u] = ei[e];
        bb[u] = d[u] >> BSH;
        lp[u] = atomicAdd(&hist[bb[u]], 1);
      } else {
        bb[u] = -1;
      }
    }
    __syncthreads();
    if (hist[t]) gbase[t] = atomicAdd(&bfill[t], hist[t]);
    __syncthreads();
#pragma unroll
    for (int u = 0; u < 8; ++u)
      if (bb[u] >= 0)
        pairs[gbase[bb[u]] + lp[u]] =
            ((unsigned int)(d[u] & (BSZ - 1)) << 17) | (unsigned int)s[u];
  }
}

__global__ __launch_bounds__(256) void gemm2_mfma(const _Float16* __restrict__ X,
                                                  const float* __restrict__ W,
                                                  const float* __restrict__ dinv,
                                                  _Float16* __restrict__ G, int nrows) {
  __shared__ _Float16 Bs[64 * 136];
  gemm_mfma_body<64, 1, true, true>(X, W, dinv, G, nrows, blockIdx.x, Bs);
}

// passC: per-bucket LDS count/scan/fill
__global__ __launch_bounds__(512) void passC(const unsigned int* __restrict__ pairs,
                                             const int* __restrict__ bstart,
                                             int* __restrict__ rowstart,
                                             int* __restrict__ deg,
                                             float* __restrict__ dinv,
                                             int* __restrict__ csr, int N) {
  __shared__ int hcnt[BSZ];
  __shared__ int lfill[BSZ];
  __shared__ int ss[512];
  __shared__ int lcsr[CAP];
  int b = blockIdx.x;
  int t = threadIdx.x;
  int lo = bstart[b], hi = bstart[b + 1];
  int cnt = hi - lo;
  int nbase = b << BSH;
  hcnt[t] = 0;
  __syncthreads();
  for (int k = lo + t; k < hi; k += 512)
    atomicAdd(&hcnt[(pairs[k] >> 17) & (BSZ - 1)], 1);
  __syncthreads();
  int v = hcnt[t];
  ss[t] = v;
  __syncthreads();
  for (int off = 1; off < 512; off <<= 1) {
    int add = (t >= off) ? ss[t - off] : 0;
    __syncthreads();
    ss[t] += add;
    __syncthreads();
  }
  int ex = ss[t] - v;
  lfill[t] = ex;
  int node = nbase + t;
  if (node < N) {
    rowstart[node] = lo + ex;
    deg[node] = v;
    dinv[node] = rsqrtf((float)(v + 1));
  }
  __syncthreads();
  bool fits = (cnt <= CAP);
  for (int k = lo + t; k < hi; k += 512) {
    unsigned int p = pairs[k];
    int pos = atomicAdd(&lfill[(p >> 17) & (BSZ - 1)], 1);
    int src = (int)(p & 0x1FFFFu);
    if (fits) lcsr[pos] = src;
    else      csr[lo + pos] = src;
  }
  __syncthreads();
  if (fits)
    for (int k = t; k < cnt; k += 512) csr[lo + k] = lcsr[k];
}

// ===== agg128 v2: 16 B/lane dwordx4 gather, 4 rows per load instruction =====
// lane = g*16 + c : group g in [0,4) owns neighbor slot k+g; lane covers
// channels c*8 .. c*8+7 (16 B of fp16). Each global_load_dwordx4 fetches
// 4 *different* rows (1 KB) instead of one 256 B row -> 4x bytes per
// outstanding-request slot; 2 such loads in flight per iteration (2 KB/wave).
// Partial sums reduced across the 4 groups with shfl_xor(16) + shfl_xor(32).
__global__ __launch_bounds__(256) void agg128(
    const __half* __restrict__ G, const int* __restrict__ csr,
    const int* __restrict__ rowstart, const int* __restrict__ deg,
    const float* __restrict__ dinv, const float* __restrict__ bias,
    __half* __restrict__ out, int n) {
  int wid = blockIdx.x * 4 + (threadIdx.x >> 6);
  if (wid >= n) return;
  int i = __builtin_amdgcn_readfirstlane(wid);
  int lane = threadIdx.x & 63;
  int g = lane >> 4;
  int c = lane & 15;
  const _Float16* Gh = (const _Float16*)G;
  float di = dinv[i];
  // self contribution (group 0 only; others weight 0; same row -> one segment)
  f16x8 self = *(const f16x8*)(Gh + (size_t)i * 128 + c * 8);
  float wself = (g == 0) ? di : 0.f;
  float a[8];
#pragma unroll
  for (int j = 0; j < 8; ++j) a[j] = wself * (float)self[j];
  int s = rowstart[i];
  int d = deg[i];
  for (int base = 0; base < d; base += 64) {
    int chunk = d - base;
    if (chunk > 64) chunk = 64;
    // pad with i: loads row i (L1-hit broadcast), weight forced to 0
    int myidx = (lane < chunk) ? csr[s + base + lane] : i;
    for (int k = 0; k < chunk; k += 8) {
      int sl0 = k + g, sl1 = k + 4 + g;
      int s0 = __shfl(myidx, sl0);
      int s1 = __shfl(myidx, sl1);
      float w0 = dinv[s0];
      float w1 = dinv[s1];
      if (sl0 >= chunk) w0 = 0.f;
      if (sl1 >= chunk) w1 = 0.f;
      f16x8 v0 = *(const f16x8*)(Gh + (size_t)s0 * 128 + c * 8);
      f16x8 v1 = *(const f16x8*)(Gh + (size_t)s1 * 128 + c * 8);
#pragma unroll
      for (int j = 0; j < 8; ++j) a[j] = fmaf(w0, (float)v0[j], a[j]);
#pragma unroll
      for (int j = 0; j < 8; ++j) a[j] = fmaf(w1, (float)v1[j], a[j]);
    }
  }
  // reduce the 4 group-partials: lanes l, l^16, l^32, l^48
#pragma unroll
  for (int j = 0; j < 8; ++j) {
    a[j] += __shfl_xor(a[j], 16);
    a[j] += __shfl_xor(a[j], 32);
  }
  if (g == 0) {
    float4 b0 = *(const float4*)(bias + c * 8);
    float4 b1 = *(const float4*)(bias + c * 8 + 4);
    f16x8 r;
    r[0] = (_Float16)fmaxf(fmaf(di, a[0], b0.x), 0.f);
    r[1] = (_Float16)fmaxf(fmaf(di, a[1], b0.y), 0.f);
    r[2] = (_Float16)fmaxf(fmaf(di, a[2], b0.z), 0.f);
    r[3] = (_Float16)fmaxf(fmaf(di, a[3], b0.w), 0.f);
    r[4] = (_Float16)fmaxf(fmaf(di, a[4], b1.x), 0.f);
    r[5] = (_Float16)fmaxf(fmaf(di, a[5], b1.y), 0.f);
    r[6] = (_Float16)fmaxf(fmaf(di, a[6], b1.z), 0.f);
    r[7] = (_Float16)fmaxf(fmaf(di, a[7], b1.w), 0.f);
    *(f16x8*)((_Float16*)out + (size_t)i * 128 + c * 8) = r;
  }
}

// ===== agg64 v2: same structure, 8 B/lane (half4), 4 rows (512 B) / load =====
__global__ __launch_bounds__(256) void agg64(
    const __half* __restrict__ G, const int* __restrict__ csr,
    const int* __restrict__ rowstart, const int* __restrict__ deg,
    const float* __restrict__ dinv, const float* __restrict__ bias,
    float* __restrict__ out, int n) {
  int wid = blockIdx.x * 4 + (threadIdx.x >> 6);
  if (wid >= n) return;
  int i = __builtin_amdgcn_readfirstlane(wid);
  int lane = threadIdx.x & 63;
  int g = lane >> 4;
  int c = lane & 15;
  const _Float16* Gh = (const _Float16*)G;
  f16x4 self = *(const f16x4*)(Gh + (size_t)i * 64 + c * 4);
  float wself = (g == 0) ? 1.f : 0.f;
  float a[4];
#pragma unroll
  for (int j = 0; j < 4; ++j) a[j] = wself * (float)self[j];
  int s = rowstart[i];
  int d = deg[i];
  for (int base = 0; base < d; base += 64) {
    int chunk = d - base;
    if (chunk > 64) chunk = 64;
    int myidx = (lane < chunk) ? csr[s + base + lane] : i;
    for (int k = 0; k < chunk; k += 8) {
      int sl0 = k + g, sl1 = k + 4 + g;
      int s0 = __shfl(myidx, sl0);
      int s1 = __shfl(myidx, sl1);
      float w0 = (sl0 < chunk) ? 1.f : 0.f;
      float w1 = (sl1 < chunk) ? 1.f : 0.f;
      f16x4 v0 = *(const f16x4*)(Gh + (size_t)s0 * 64 + c * 4);
      f16x4 v1 = *(const f16x4*)(Gh + (size_t)s1 * 64 + c * 4);
#pragma unroll
      for (int j = 0; j < 4; ++j) a[j] = fmaf(w0, (float)v0[j], a[j]);
#pragma unroll
      for (int j = 0; j < 4; ++j) a[j] = fmaf(w1, (float)v1[j], a[j]);
    }
  }
#pragma unroll
  for (int j = 0; j < 4; ++j) {
    a[j] += __shfl_xor(a[j], 16);
    a[j] += __shfl_xor(a[j], 32);
  }
  if (g == 0) {
    float di = dinv[i];
    float4 bv = *(const float4*)(bias + c * 4);
    float4 r;
    r.x = fmaxf(fmaf(di, a[0], bv.x), 0.f);
    r.y = fmaxf(fmaf(di, a[1], bv.y), 0.f);
    r.z = fmaxf(fmaf(di, a[2], bv.z), 0.f);
    r.w = fmaxf(fmaf(di, a[3], bv.w), 0.f);
    *(float4*)(out + (size_t)i * 64 + c * 4) = r;
  }
}

// ================= launch =================
extern "C" void kernel_launch(void* const* d_in, const int* in_sizes, int n_in,
                              void* d_out, int out_size, void* d_ws, size_t ws_size,
                              hipStream_t stream) {
  const float* x  = (const float*)d_in[0];
  const int*   ei = (const int*)d_in[1];
  const float* W1 = (const float*)d_in[2];
  const float* b1 = (const float*)d_in[3];
  const float* W2 = (const float*)d_in[4];
  const float* b2 = (const float*)d_in[5];
  float* out = (float*)d_out;

  const int N = in_sizes[0] / 128;
  const int E = in_sizes[1] / 2;
  const int NB = (N + BSZ - 1) >> BSH;

  char* base = (char*)d_ws;
  size_t off = 0;
  auto alloc = [&](size_t bytes) -> void* {
    void* p = base + off;
    off += (bytes + 255) & ~(size_t)255;
    return p;
  };
  int*          bcount   = (int*)alloc(256 * 4);
  int*          bstart   = (int*)alloc(260 * 4);
  int*          bfill    = (int*)alloc(256 * 4);
  int*          deg      = (int*)alloc((size_t)N * 4);
  int*          rowstart = (int*)alloc((size_t)N * 4);
  float*        dinv     = (float*)alloc((size_t)N * 4);
  int*          csr      = (int*)alloc((size_t)E * 4);
  unsigned int* pairs    = (unsigned int*)alloc((size_t)E * 4);
  __half*       g1       = (__half*)alloc((size_t)N * 128 * 2);  // reused for g2
  __half*       x2       = (__half*)alloc((size_t)N * 128 * 2);

  hipMemsetAsync(bcount, 0, 256 * 4, stream);
  passA<<<512, 256, 0, stream>>>(ei, bcount, E, NB);
  scanB<<<1, 256, 0, stream>>>(bcount, bstart, bfill, NB, E);

  int GB = (N + 127) / 128;
  int PB = (E + 2047) / 2048;
  fused_gemm_passB<<<GB + PB, 256, 0, stream>>>(x, W1, (_Float16*)g1, N, GB, ei,
                                                bfill, pairs, E, PB);
  passC<<<NB, 512, 0, stream>>>(pairs, bstart, rowstart, deg, dinv, csr, N);

  agg128<<<(N + 3) / 4, 256, 0, stream>>>(g1, csr, rowstart, deg, dinv, b1, x2, N);
  int G2B = (N + 255) / 256;
  gemm2_mfma<<<G2B, 256, 0, stream>>>((const _Float16*)x2, W2, dinv,
                                      (_Float16*)g1, N);
  agg64<<<(N + 3) / 4, 256, 0, stream>>>(g1, csr, rowstart, deg, dinv, b2, out, N);
}